// Round 1
// baseline (3538.242 us; speedup 1.0000x reference)
//
#include <hip/hip_runtime.h>

#define N_NODES 50000
#define N_EDGES 600000
#define D 128

__global__ void k_count(const int* __restrict__ dst, int* __restrict__ cnt) {
    int e = blockIdx.x * blockDim.x + threadIdx.x;
    if (e < N_EDGES) atomicAdd(&cnt[dst[e]], 1);
}

// One thread per (edge, float4-chunk): 600000 * 32 threads.
__global__ void k_scatter(const int* __restrict__ src, const int* __restrict__ dst,
                          const float* __restrict__ x, float* __restrict__ agg) {
    int tid = blockIdx.x * blockDim.x + threadIdx.x;
    if (tid >= N_EDGES * 32) return;
    int e = tid >> 5;
    int q = tid & 31;
    int s = src[e];
    int d = dst[e];
    const float4 v = ((const float4*)(x + (size_t)s * D))[q];
    float* a = agg + (size_t)d * D + q * 4;
    atomicAdd(a + 0, v.x);
    atomicAdd(a + 1, v.y);
    atomicAdd(a + 2, v.z);
    atomicAdd(a + 3, v.w);
}

// out[node,f] = (RELU?) ( mean_row . Wl[f,:] + b[f] + x_row . Wr[f,:] )
// 256 threads/block = 2 nodes/block (128 feature-threads per node).
template <bool RELU>
__global__ void k_layer(const float* __restrict__ agg, const int* __restrict__ cnt,
                        const float* __restrict__ xin,
                        const float* __restrict__ Wl, const float* __restrict__ b,
                        const float* __restrict__ Wr, float* __restrict__ out) {
    __shared__ float4 s_m[2][32];  // mean rows for the 2 nodes
    __shared__ float4 s_x[2][32];  // x rows

    int local = threadIdx.x;
    int nl = local >> 7;       // which node in block
    int f = local & 127;       // output feature
    int node = blockIdx.x * 2 + nl;  // grid = 25000 exactly covers 50000

    float inv = 1.0f / fmaxf((float)cnt[node], 1.0f);
    ((float*)s_m[nl])[f] = agg[node * D + f] * inv;
    ((float*)s_x[nl])[f] = xin[node * D + f];
    __syncthreads();

    float acc = b[f];
    const float4* wl4 = (const float4*)(Wl + f * D);
    const float4* wr4 = (const float4*)(Wr + f * D);
#pragma unroll 8
    for (int k = 0; k < 32; ++k) {
        float4 m = s_m[nl][k];
        float4 xr = s_x[nl][k];
        float4 wl = wl4[k];
        float4 wr = wr4[k];
        acc += m.x * wl.x + m.y * wl.y + m.z * wl.z + m.w * wl.w;
        acc += xr.x * wr.x + xr.y * wr.y + xr.z * wr.z + xr.w * wr.w;
    }
    if (RELU) acc = acc > 0.0f ? acc : 0.2f * acc;
    out[node * D + f] = acc;
}

extern "C" void kernel_launch(void* const* d_in, const int* in_sizes, int n_in,
                              void* d_out, int out_size, void* d_ws, size_t ws_size,
                              hipStream_t stream) {
    (void)in_sizes; (void)n_in; (void)out_size; (void)ws_size;

    const float* x   = (const float*)d_in[0];
    const int*   ei  = (const int*)d_in[1];
    const float* W1l = (const float*)d_in[2];
    const float* b1  = (const float*)d_in[3];
    const float* W1r = (const float*)d_in[4];
    const float* W2l = (const float*)d_in[5];
    const float* b2  = (const float*)d_in[6];
    const float* W2r = (const float*)d_in[7];

    const int* src = ei;
    const int* dst = ei + N_EDGES;

    char* ws = (char*)d_ws;
    int*   cnt = (int*)ws;                               // 200 KB (padded to 204800)
    float* agg = (float*)(ws + 204800);                  // 25.6 MB
    float* h   = (float*)(ws + 204800 + (size_t)N_NODES * D * 4);  // 25.6 MB
    float* out = (float*)d_out;

    const size_t agg_bytes = (size_t)N_NODES * D * sizeof(float);

    hipMemsetAsync(cnt, 0, N_NODES * sizeof(int), stream);
    hipMemsetAsync(agg, 0, agg_bytes, stream);
    k_count<<<(N_EDGES + 255) / 256, 256, 0, stream>>>(dst, cnt);
    k_scatter<<<(N_EDGES * 32 + 255) / 256, 256, 0, stream>>>(src, dst, x, agg);
    k_layer<true><<<N_NODES / 2, 256, 0, stream>>>(agg, cnt, x, W1l, b1, W1r, h);

    hipMemsetAsync(agg, 0, agg_bytes, stream);
    k_scatter<<<(N_EDGES * 32 + 255) / 256, 256, 0, stream>>>(src, dst, h, agg);
    k_layer<false><<<N_NODES / 2, 256, 0, stream>>>(agg, cnt, h, W2l, b2, W2r, out);
}

// Round 2
// 799.205 us; speedup vs baseline: 4.4272x; 4.4272x over previous
//
#include <hip/hip_runtime.h>

#define N_NODES 50000
#define N_EDGES 600000
#define D 128

// ---------------- CSR build ----------------

__global__ void k_count(const int* __restrict__ dst, int* __restrict__ cnt) {
    int e = blockIdx.x * blockDim.x + threadIdx.x;
    if (e < N_EDGES) atomicAdd(&cnt[dst[e]], 1);
}

// Single-block exclusive scan over 50000 counts -> off[0..N], cursor copy.
__global__ void k_scan(const int* __restrict__ cnt, int* __restrict__ off,
                       int* __restrict__ cursor) {
    __shared__ int ps[1024];
    const int t = threadIdx.x;
    const int per = 49;  // 1024*49 = 50176 >= 50000
    const int base = t * per;
    int sum = 0;
    for (int i = 0; i < per; ++i) {
        int idx = base + i;
        if (idx < N_NODES) sum += cnt[idx];
    }
    ps[t] = sum;
    __syncthreads();
    // Hillis-Steele inclusive scan over the 1024 partials
    for (int d = 1; d < 1024; d <<= 1) {
        int v = (t >= d) ? ps[t - d] : 0;
        __syncthreads();
        ps[t] += v;
        __syncthreads();
    }
    int run = (t == 0) ? 0 : ps[t - 1];
    for (int i = 0; i < per; ++i) {
        int idx = base + i;
        if (idx < N_NODES) {
            off[idx] = run;
            cursor[idx] = run;
            run += cnt[idx];
        }
    }
    if (t == 1023) off[N_NODES] = N_EDGES;
}

__global__ void k_bucket(const int* __restrict__ src, const int* __restrict__ dst,
                         int* __restrict__ cursor, int* __restrict__ ebuf) {
    int e = blockIdx.x * blockDim.x + threadIdx.x;
    if (e < N_EDGES) {
        int p = atomicAdd(&cursor[dst[e]], 1);
        ebuf[p] = src[e];
    }
}

// ---------------- pull-gather mean ----------------
// One thread per (node, float4 chunk): 50000*32 threads. Wave covers 2 nodes;
// x-row reads are 512B contiguous segments per half-wave (coalesced).
__global__ void k_gather(const int* __restrict__ off, const int* __restrict__ ebuf,
                         const float* __restrict__ xin, float* __restrict__ mean) {
    int tid = blockIdx.x * blockDim.x + threadIdx.x;
    int node = tid >> 5;
    int q = tid & 31;
    int s0 = off[node], s1 = off[node + 1];
    float4 acc = make_float4(0.f, 0.f, 0.f, 0.f);
    for (int e = s0; e < s1; ++e) {
        int s = ebuf[e];
        float4 v = ((const float4*)(xin + (size_t)s * D))[q];
        acc.x += v.x; acc.y += v.y; acc.z += v.z; acc.w += v.w;
    }
    float inv = (s1 > s0) ? 1.0f / (float)(s1 - s0) : 0.0f;
    acc.x *= inv; acc.y *= inv; acc.z *= inv; acc.w *= inv;
    ((float4*)(mean + (size_t)node * D))[q] = acc;
}

// ---------------- fused dual-GEMV layer ----------------
// out[n,f] = (leaky?)( mean[n,:] . Wl[f,:] + b[f] + x[n,:] . Wr[f,:] )
// Block = 256 threads, 16 nodes/block (grid 3125). Register tile: 2 f x 4 nodes.
// LDS reads are wave-uniform (ng constant within a wave) -> broadcast, 0 conflicts.
template <bool RELU>
__global__ void __launch_bounds__(256) k_layer(
    const float* __restrict__ mean, const float* __restrict__ xin,
    const float* __restrict__ Wl, const float* __restrict__ b,
    const float* __restrict__ Wr, float* __restrict__ out) {
    __shared__ float4 s_m[16][32];
    __shared__ float4 s_x[16][32];
    const int t = threadIdx.x;
    const int node0 = blockIdx.x * 16;

    for (int sidx = t; sidx < 512; sidx += 256) {
        int nl = sidx >> 5, c = sidx & 31;
        s_m[nl][c] = ((const float4*)(mean + (size_t)(node0 + nl) * D))[c];
        s_x[nl][c] = ((const float4*)(xin + (size_t)(node0 + nl) * D))[c];
    }
    __syncthreads();

    const int fp = t & 63;   // feature pair id: f0 = 2*fp
    const int ng = t >> 6;   // node group: nodes ng*4 .. ng*4+3
    const int f0 = fp * 2;

    float acc0[4], acc1[4];
    const float b0 = b[f0], b1 = b[f0 + 1];
    for (int j = 0; j < 4; ++j) { acc0[j] = b0; acc1[j] = b1; }

    const float4* wl0p = (const float4*)(Wl + (size_t)f0 * D);
    const float4* wl1p = (const float4*)(Wl + (size_t)(f0 + 1) * D);
    const float4* wr0p = (const float4*)(Wr + (size_t)f0 * D);
    const float4* wr1p = (const float4*)(Wr + (size_t)(f0 + 1) * D);

#pragma unroll 4
    for (int kc = 0; kc < 32; ++kc) {
        float4 wl0 = wl0p[kc], wl1 = wl1p[kc];
        float4 wr0 = wr0p[kc], wr1 = wr1p[kc];
#pragma unroll
        for (int j = 0; j < 4; ++j) {
            int nl = ng * 4 + j;
            float4 m = s_m[nl][kc];
            float4 xr = s_x[nl][kc];
            acc0[j] += m.x * wl0.x + m.y * wl0.y + m.z * wl0.z + m.w * wl0.w
                     + xr.x * wr0.x + xr.y * wr0.y + xr.z * wr0.z + xr.w * wr0.w;
            acc1[j] += m.x * wl1.x + m.y * wl1.y + m.z * wl1.z + m.w * wl1.w
                     + xr.x * wr1.x + xr.y * wr1.y + xr.z * wr1.z + xr.w * wr1.w;
        }
    }

    for (int j = 0; j < 4; ++j) {
        int node = node0 + ng * 4 + j;
        float a0 = acc0[j], a1 = acc1[j];
        if (RELU) {
            a0 = a0 > 0.f ? a0 : 0.2f * a0;
            a1 = a1 > 0.f ? a1 : 0.2f * a1;
        }
        ((float2*)(out + (size_t)node * D))[fp] = make_float2(a0, a1);
    }
}

// ---------------- host launch ----------------

extern "C" void kernel_launch(void* const* d_in, const int* in_sizes, int n_in,
                              void* d_out, int out_size, void* d_ws, size_t ws_size,
                              hipStream_t stream) {
    (void)in_sizes; (void)n_in; (void)out_size; (void)ws_size;

    const float* x   = (const float*)d_in[0];
    const int*   ei  = (const int*)d_in[1];
    const float* W1l = (const float*)d_in[2];
    const float* b1  = (const float*)d_in[3];
    const float* W1r = (const float*)d_in[4];
    const float* W2l = (const float*)d_in[5];
    const float* b2  = (const float*)d_in[6];
    const float* W2r = (const float*)d_in[7];

    const int* src = ei;
    const int* dst = ei + N_EDGES;

    char* ws = (char*)d_ws;
    int*   cnt    = (int*)(ws + 0);          // 200,000 B
    int*   off    = (int*)(ws + 200064);     // 200,004 B
    int*   cursor = (int*)(ws + 400128);     // 200,000 B
    int*   ebuf   = (int*)(ws + 600192);     // 2,400,000 B
    float* mean   = (float*)(ws + 3000192);  // 25,600,000 B
    float* h      = (float*)(ws + 28600192); // 25,600,000 B
    float* out    = (float*)d_out;

    hipMemsetAsync(cnt, 0, N_NODES * sizeof(int), stream);
    k_count<<<(N_EDGES + 255) / 256, 256, 0, stream>>>(dst, cnt);
    k_scan<<<1, 1024, 0, stream>>>(cnt, off, cursor);
    k_bucket<<<(N_EDGES + 255) / 256, 256, 0, stream>>>(src, dst, cursor, ebuf);

    k_gather<<<(N_NODES * 32) / 256, 256, 0, stream>>>(off, ebuf, x, mean);
    k_layer<true><<<N_NODES / 16, 256, 0, stream>>>(mean, x, W1l, b1, W1r, h);

    k_gather<<<(N_NODES * 32) / 256, 256, 0, stream>>>(off, ebuf, h, mean);
    k_layer<false><<<N_NODES / 16, 256, 0, stream>>>(mean, h, W2l, b2, W2r, out);
}

// Round 3
// 469.898 us; speedup vs baseline: 7.5298x; 1.7008x over previous
//
#include <hip/hip_runtime.h>

#define N_NODES 50000
#define N_EDGES 600000
#define D 128
#define BN 128   // nodes per block in k_layer
#define BK 32    // k-chunk

// ---------------- CSR build ----------------

__global__ void k_count(const int* __restrict__ dst, int* __restrict__ cnt) {
    int e = blockIdx.x * blockDim.x + threadIdx.x;
    if (e < N_EDGES) atomicAdd(&cnt[dst[e]], 1);
}

__global__ void k_scan(const int* __restrict__ cnt, int* __restrict__ off,
                       int* __restrict__ cursor) {
    __shared__ int ps[1024];
    const int t = threadIdx.x;
    const int per = 49;  // 1024*49 >= 50000
    const int base = t * per;
    int sum = 0;
    for (int i = 0; i < per; ++i) {
        int idx = base + i;
        if (idx < N_NODES) sum += cnt[idx];
    }
    ps[t] = sum;
    __syncthreads();
    for (int d = 1; d < 1024; d <<= 1) {
        int v = (t >= d) ? ps[t - d] : 0;
        __syncthreads();
        ps[t] += v;
        __syncthreads();
    }
    int run = (t == 0) ? 0 : ps[t - 1];
    for (int i = 0; i < per; ++i) {
        int idx = base + i;
        if (idx < N_NODES) {
            off[idx] = run;
            cursor[idx] = run;
            run += cnt[idx];
        }
    }
    if (t == 1023) off[N_NODES] = N_EDGES;
}

__global__ void k_bucket(const int* __restrict__ src, const int* __restrict__ dst,
                         int* __restrict__ cursor, int* __restrict__ ebuf) {
    int e = blockIdx.x * blockDim.x + threadIdx.x;
    if (e < N_EDGES) {
        int p = atomicAdd(&cursor[dst[e]], 1);
        ebuf[p] = src[e];
    }
}

// ---------------- pull-gather mean ----------------
// One thread per (node, float4 chunk). Unrolled by 2 edges for MLP.
__global__ void k_gather(const int* __restrict__ off, const int* __restrict__ ebuf,
                         const float* __restrict__ xin, float* __restrict__ mean) {
    int tid = blockIdx.x * blockDim.x + threadIdx.x;
    int node = tid >> 5;
    int q = tid & 31;
    int s0 = off[node], s1 = off[node + 1];
    float4 acc = make_float4(0.f, 0.f, 0.f, 0.f);
    int e = s0;
    for (; e + 2 <= s1; e += 2) {
        int sa = ebuf[e], sb = ebuf[e + 1];
        float4 va = ((const float4*)(xin + (size_t)sa * D))[q];
        float4 vb = ((const float4*)(xin + (size_t)sb * D))[q];
        acc.x += va.x; acc.y += va.y; acc.z += va.z; acc.w += va.w;
        acc.x += vb.x; acc.y += vb.y; acc.z += vb.z; acc.w += vb.w;
    }
    if (e < s1) {
        int sa = ebuf[e];
        float4 va = ((const float4*)(xin + (size_t)sa * D))[q];
        acc.x += va.x; acc.y += va.y; acc.z += va.z; acc.w += va.w;
    }
    float inv = (s1 > s0) ? 1.0f / (float)(s1 - s0) : 0.0f;
    acc.x *= inv; acc.y *= inv; acc.z *= inv; acc.w *= inv;
    ((float4*)(mean + (size_t)node * D))[q] = acc;
}

// ---------------- LDS-tiled dual GEMM layer ----------------
// C[n,f] = (leaky?)( mean[n,:].Wl[f,:] + x[n,:].Wr[f,:] + b[f] )
// Block: 128 nodes x 128 features, 256 threads, 8x8 register tile.
// Thread (trow,tcol): nodes {trow + 16j}, features {tcol*8 .. +7}.
template <bool RELU>
__global__ void __launch_bounds__(256) k_layer(
    const float* __restrict__ mean, const float* __restrict__ xin,
    const float* __restrict__ Wl, const float* __restrict__ bias,
    const float* __restrict__ Wr, float* __restrict__ out) {
    __shared__ float A_s[BN][36];      // node rows, pad 36 (16B-aligned, conflict-free)
    __shared__ float B_s[BK][D];       // W transposed: B_s[k][f]

    const int t = threadIdx.x;
    const int node0 = blockIdx.x * BN;
    const int tcol = t & 15;
    const int trow = t >> 4;
    const int f0 = tcol * 8;

    float acc[8][8];
#pragma unroll
    for (int j = 0; j < 8; ++j)
#pragma unroll
        for (int i = 0; i < 8; ++i) acc[j][i] = 0.f;

    for (int chunk = 0; chunk < 8; ++chunk) {
        const float* Asrc = (chunk < 4) ? mean : xin;
        const float* Wsrc = (chunk < 4) ? Wl : Wr;
        const int kc = (chunk & 3) * BK;

        // stage A: 128 rows x 32 floats (coalesced 128B segments per row)
#pragma unroll
        for (int l = 0; l < 4; ++l) {
            int idx = l * 256 + t;
            int row = idx >> 3, c4 = (idx & 7) * 4;
            float4 v = make_float4(0.f, 0.f, 0.f, 0.f);
            int node = node0 + row;
            if (node < N_NODES)
                v = *(const float4*)(Asrc + (size_t)node * D + kc + c4);
            *(float4*)(&A_s[row][c4]) = v;
        }
        // stage B transposed: B_s[k][f] = W[f][kc+k]; coalesced global reads
#pragma unroll
        for (int l = 0; l < 4; ++l) {
            int fi = l * 256 + t;
            int f = fi >> 3, q = fi & 7;
            float4 v = *(const float4*)(Wsrc + (size_t)f * D + kc + q * 4);
            B_s[q * 4 + 0][f] = v.x;
            B_s[q * 4 + 1][f] = v.y;
            B_s[q * 4 + 2][f] = v.z;
            B_s[q * 4 + 3][f] = v.w;
        }
        __syncthreads();

#pragma unroll 2
        for (int k4 = 0; k4 < BK; k4 += 4) {
            float4 a[8];
#pragma unroll
            for (int j = 0; j < 8; ++j)
                a[j] = *(const float4*)(&A_s[trow + 16 * j][k4]);
#pragma unroll
            for (int kk = 0; kk < 4; ++kk) {
                float4 b0 = *(const float4*)(&B_s[k4 + kk][f0]);
                float4 b1 = *(const float4*)(&B_s[k4 + kk][f0 + 4]);
                float bb[8] = {b0.x, b0.y, b0.z, b0.w, b1.x, b1.y, b1.z, b1.w};
#pragma unroll
                for (int j = 0; j < 8; ++j) {
                    float av = (kk == 0) ? a[j].x : (kk == 1) ? a[j].y
                             : (kk == 2) ? a[j].z : a[j].w;
#pragma unroll
                    for (int i = 0; i < 8; ++i)
                        acc[j][i] += av * bb[i];
                }
            }
        }
        __syncthreads();
    }

    // epilogue: bias (+leaky relu), 2x float4 stores per row
    float4 bv0 = *(const float4*)(bias + f0);
    float4 bv1 = *(const float4*)(bias + f0 + 4);
#pragma unroll
    for (int j = 0; j < 8; ++j) {
        int node = node0 + trow + 16 * j;
        if (node >= N_NODES) continue;
        float o[8];
        o[0] = acc[j][0] + bv0.x; o[1] = acc[j][1] + bv0.y;
        o[2] = acc[j][2] + bv0.z; o[3] = acc[j][3] + bv0.w;
        o[4] = acc[j][4] + bv1.x; o[5] = acc[j][5] + bv1.y;
        o[6] = acc[j][6] + bv1.z; o[7] = acc[j][7] + bv1.w;
        if (RELU) {
#pragma unroll
            for (int i = 0; i < 8; ++i) o[i] = o[i] > 0.f ? o[i] : 0.2f * o[i];
        }
        float* orow = out + (size_t)node * D + f0;
        *(float4*)(orow)     = make_float4(o[0], o[1], o[2], o[3]);
        *(float4*)(orow + 4) = make_float4(o[4], o[5], o[6], o[7]);
    }
}

// ---------------- host launch ----------------

extern "C" void kernel_launch(void* const* d_in, const int* in_sizes, int n_in,
                              void* d_out, int out_size, void* d_ws, size_t ws_size,
                              hipStream_t stream) {
    (void)in_sizes; (void)n_in; (void)out_size; (void)ws_size;

    const float* x   = (const float*)d_in[0];
    const int*   ei  = (const int*)d_in[1];
    const float* W1l = (const float*)d_in[2];
    const float* b1  = (const float*)d_in[3];
    const float* W1r = (const float*)d_in[4];
    const float* W2l = (const float*)d_in[5];
    const float* b2  = (const float*)d_in[6];
    const float* W2r = (const float*)d_in[7];

    const int* src = ei;
    const int* dst = ei + N_EDGES;

    char* ws = (char*)d_ws;
    int*   cnt    = (int*)(ws + 0);          // 200,000 B
    int*   off    = (int*)(ws + 200064);     // 200,004 B
    int*   cursor = (int*)(ws + 400128);     // 200,000 B
    int*   ebuf   = (int*)(ws + 600192);     // 2,400,000 B
    float* mean   = (float*)(ws + 3000192);  // 25,600,000 B
    float* h      = (float*)(ws + 28600192); // 25,600,000 B
    float* out    = (float*)d_out;

    hipMemsetAsync(cnt, 0, N_NODES * sizeof(int), stream);
    k_count<<<(N_EDGES + 255) / 256, 256, 0, stream>>>(dst, cnt);
    k_scan<<<1, 1024, 0, stream>>>(cnt, off, cursor);
    k_bucket<<<(N_EDGES + 255) / 256, 256, 0, stream>>>(src, dst, cursor, ebuf);

    k_gather<<<(N_NODES * 32) / 256, 256, 0, stream>>>(off, ebuf, x, mean);
    k_layer<true><<<(N_NODES + BN - 1) / BN, 256, 0, stream>>>(mean, x, W1l, b1, W1r, h);

    k_gather<<<(N_NODES * 32) / 256, 256, 0, stream>>>(off, ebuf, h, mean);
    k_layer<false><<<(N_NODES + BN - 1) / BN, 256, 0, stream>>>(mean, h, W2l, b2, W2r, out);
}

// Round 4
// 351.467 us; speedup vs baseline: 10.0671x; 1.3370x over previous
//
#include <hip/hip_runtime.h>

#define N_NODES 50000
#define N_EDGES 600000
#define D 128
#define BN 128   // nodes per block in k_layer
#define BK 32    // k-chunk
#define SCAN_BLOCKS ((N_NODES + 255) / 256)   // 196

// ---------------- CSR build ----------------

__global__ void k_count(const int* __restrict__ dst, int* __restrict__ cnt) {
    int e = blockIdx.x * blockDim.x + threadIdx.x;
    if (e < N_EDGES) atomicAdd(&cnt[dst[e]], 1);
}

// Multi-block scan, stage 1: per-block local exclusive scan + block totals.
__global__ void k_scan1(const int* __restrict__ cnt, int* __restrict__ off,
                        int* __restrict__ partial) {
    __shared__ int sdata[256];
    const int t = threadIdx.x;
    const int i = blockIdx.x * 256 + t;
    int v = (i < N_NODES) ? cnt[i] : 0;
    sdata[t] = v;
    __syncthreads();
    for (int d = 1; d < 256; d <<= 1) {
        int u = (t >= d) ? sdata[t - d] : 0;
        __syncthreads();
        sdata[t] += u;
        __syncthreads();
    }
    if (i < N_NODES) off[i] = sdata[t] - v;  // local exclusive
    if (t == 255) partial[blockIdx.x] = sdata[255];
}

// Stage 2: exclusive scan of the block totals (196 values, one block).
__global__ void k_scan2(int* __restrict__ partial) {
    __shared__ int sdata[256];
    const int t = threadIdx.x;
    int v = (t < SCAN_BLOCKS) ? partial[t] : 0;
    sdata[t] = v;
    __syncthreads();
    for (int d = 1; d < 256; d <<= 1) {
        int u = (t >= d) ? sdata[t - d] : 0;
        __syncthreads();
        sdata[t] += u;
        __syncthreads();
    }
    if (t < SCAN_BLOCKS) partial[t] = sdata[t] - v;  // exclusive
}

// Stage 3: add block offsets; emit off + cursor.
__global__ void k_scan3(int* __restrict__ off, const int* __restrict__ partial,
                        int* __restrict__ cursor) {
    const int i = blockIdx.x * 256 + threadIdx.x;
    if (i < N_NODES) {
        int o = off[i] + partial[blockIdx.x];
        off[i] = o;
        cursor[i] = o;
    }
    if (i == 0) off[N_NODES] = N_EDGES;
}

__global__ void k_bucket(const int* __restrict__ src, const int* __restrict__ dst,
                         int* __restrict__ cursor, int* __restrict__ ebuf) {
    int e = blockIdx.x * blockDim.x + threadIdx.x;
    if (e < N_EDGES) {
        int p = atomicAdd(&cursor[dst[e]], 1);
        ebuf[p] = src[e];
    }
}

// ---------------- pull-gather mean ----------------
// One thread per (node, float4 chunk). Unrolled by 4 edges for MLP.
__global__ void k_gather(const int* __restrict__ off, const int* __restrict__ ebuf,
                         const float* __restrict__ xin, float* __restrict__ mean) {
    int tid = blockIdx.x * blockDim.x + threadIdx.x;
    int node = tid >> 5;
    int q = tid & 31;
    int s0 = off[node], s1 = off[node + 1];
    float4 acc = make_float4(0.f, 0.f, 0.f, 0.f);
    int e = s0;
    for (; e + 4 <= s1; e += 4) {
        int sa = ebuf[e], sb = ebuf[e + 1], sc = ebuf[e + 2], sd = ebuf[e + 3];
        float4 va = ((const float4*)(xin + (size_t)sa * D))[q];
        float4 vb = ((const float4*)(xin + (size_t)sb * D))[q];
        float4 vc = ((const float4*)(xin + (size_t)sc * D))[q];
        float4 vd = ((const float4*)(xin + (size_t)sd * D))[q];
        acc.x += va.x + vb.x + vc.x + vd.x;
        acc.y += va.y + vb.y + vc.y + vd.y;
        acc.z += va.z + vb.z + vc.z + vd.z;
        acc.w += va.w + vb.w + vc.w + vd.w;
    }
    for (; e < s1; ++e) {
        int sa = ebuf[e];
        float4 va = ((const float4*)(xin + (size_t)sa * D))[q];
        acc.x += va.x; acc.y += va.y; acc.z += va.z; acc.w += va.w;
    }
    float inv = (s1 > s0) ? 1.0f / (float)(s1 - s0) : 0.0f;
    acc.x *= inv; acc.y *= inv; acc.z *= inv; acc.w *= inv;
    ((float4*)(mean + (size_t)node * D))[q] = acc;
}

// ---------------- LDS-tiled dual GEMM layer ----------------
template <bool RELU>
__global__ void __launch_bounds__(256) k_layer(
    const float* __restrict__ mean, const float* __restrict__ xin,
    const float* __restrict__ Wl, const float* __restrict__ bias,
    const float* __restrict__ Wr, float* __restrict__ out) {
    __shared__ float A_s[BN][36];
    __shared__ float B_s[BK][D];

    const int t = threadIdx.x;
    const int node0 = blockIdx.x * BN;
    const int tcol = t & 15;
    const int trow = t >> 4;
    const int f0 = tcol * 8;

    float acc[8][8];
#pragma unroll
    for (int j = 0; j < 8; ++j)
#pragma unroll
        for (int i = 0; i < 8; ++i) acc[j][i] = 0.f;

    for (int chunk = 0; chunk < 8; ++chunk) {
        const float* Asrc = (chunk < 4) ? mean : xin;
        const float* Wsrc = (chunk < 4) ? Wl : Wr;
        const int kc = (chunk & 3) * BK;

#pragma unroll
        for (int l = 0; l < 4; ++l) {
            int idx = l * 256 + t;
            int row = idx >> 3, c4 = (idx & 7) * 4;
            float4 v = make_float4(0.f, 0.f, 0.f, 0.f);
            int node = node0 + row;
            if (node < N_NODES)
                v = *(const float4*)(Asrc + (size_t)node * D + kc + c4);
            *(float4*)(&A_s[row][c4]) = v;
        }
#pragma unroll
        for (int l = 0; l < 4; ++l) {
            int fi = l * 256 + t;
            int f = fi >> 3, q = fi & 7;
            float4 v = *(const float4*)(Wsrc + (size_t)f * D + kc + q * 4);
            B_s[q * 4 + 0][f] = v.x;
            B_s[q * 4 + 1][f] = v.y;
            B_s[q * 4 + 2][f] = v.z;
            B_s[q * 4 + 3][f] = v.w;
        }
        __syncthreads();

#pragma unroll 2
        for (int k4 = 0; k4 < BK; k4 += 4) {
            float4 a[8];
#pragma unroll
            for (int j = 0; j < 8; ++j)
                a[j] = *(const float4*)(&A_s[trow + 16 * j][k4]);
#pragma unroll
            for (int kk = 0; kk < 4; ++kk) {
                float4 b0 = *(const float4*)(&B_s[k4 + kk][f0]);
                float4 b1 = *(const float4*)(&B_s[k4 + kk][f0 + 4]);
                float bb[8] = {b0.x, b0.y, b0.z, b0.w, b1.x, b1.y, b1.z, b1.w};
#pragma unroll
                for (int j = 0; j < 8; ++j) {
                    float av = (kk == 0) ? a[j].x : (kk == 1) ? a[j].y
                             : (kk == 2) ? a[j].z : a[j].w;
#pragma unroll
                    for (int i = 0; i < 8; ++i)
                        acc[j][i] += av * bb[i];
                }
            }
        }
        __syncthreads();
    }

    float4 bv0 = *(const float4*)(bias + f0);
    float4 bv1 = *(const float4*)(bias + f0 + 4);
#pragma unroll
    for (int j = 0; j < 8; ++j) {
        int node = node0 + trow + 16 * j;
        if (node >= N_NODES) continue;
        float o[8];
        o[0] = acc[j][0] + bv0.x; o[1] = acc[j][1] + bv0.y;
        o[2] = acc[j][2] + bv0.z; o[3] = acc[j][3] + bv0.w;
        o[4] = acc[j][4] + bv1.x; o[5] = acc[j][5] + bv1.y;
        o[6] = acc[j][6] + bv1.z; o[7] = acc[j][7] + bv1.w;
        if (RELU) {
#pragma unroll
            for (int i = 0; i < 8; ++i) o[i] = o[i] > 0.f ? o[i] : 0.2f * o[i];
        }
        float* orow = out + (size_t)node * D + f0;
        *(float4*)(orow)     = make_float4(o[0], o[1], o[2], o[3]);
        *(float4*)(orow + 4) = make_float4(o[4], o[5], o[6], o[7]);
    }
}

// ---------------- host launch ----------------

extern "C" void kernel_launch(void* const* d_in, const int* in_sizes, int n_in,
                              void* d_out, int out_size, void* d_ws, size_t ws_size,
                              hipStream_t stream) {
    (void)in_sizes; (void)n_in; (void)out_size; (void)ws_size;

    const float* x   = (const float*)d_in[0];
    const int*   ei  = (const int*)d_in[1];
    const float* W1l = (const float*)d_in[2];
    const float* b1  = (const float*)d_in[3];
    const float* W1r = (const float*)d_in[4];
    const float* W2l = (const float*)d_in[5];
    const float* b2  = (const float*)d_in[6];
    const float* W2r = (const float*)d_in[7];

    const int* src = ei;
    const int* dst = ei + N_EDGES;

    char* ws = (char*)d_ws;
    int*   cnt     = (int*)(ws + 0);          // 200,000 B
    int*   off     = (int*)(ws + 200064);     // 200,004 B
    int*   cursor  = (int*)(ws + 400128);     // 200,000 B
    int*   partial = (int*)(ws + 600192);     // 784 B (pad to 1024)
    int*   ebuf    = (int*)(ws + 601216);     // 2,400,000 B
    float* mean    = (float*)(ws + 3001216);  // 25,600,000 B
    float* h       = (float*)(ws + 28601216); // 25,600,000 B
    float* out     = (float*)d_out;

    hipMemsetAsync(cnt, 0, N_NODES * sizeof(int), stream);
    k_count<<<(N_EDGES + 255) / 256, 256, 0, stream>>>(dst, cnt);
    k_scan1<<<SCAN_BLOCKS, 256, 0, stream>>>(cnt, off, partial);
    k_scan2<<<1, 256, 0, stream>>>(partial);
    k_scan3<<<SCAN_BLOCKS, 256, 0, stream>>>(off, partial, cursor);
    k_bucket<<<(N_EDGES + 255) / 256, 256, 0, stream>>>(src, dst, cursor, ebuf);

    k_gather<<<(N_NODES * 32) / 256, 256, 0, stream>>>(off, ebuf, x, mean);
    k_layer<true><<<(N_NODES + BN - 1) / BN, 256, 0, stream>>>(mean, x, W1l, b1, W1r, h);

    k_gather<<<(N_NODES * 32) / 256, 256, 0, stream>>>(off, ebuf, h, mean);
    k_layer<false><<<(N_NODES + BN - 1) / BN, 256, 0, stream>>>(mean, h, W2l, b2, W2r, out);
}

// Round 5
// 344.706 us; speedup vs baseline: 10.2645x; 1.0196x over previous
//
#include <hip/hip_runtime.h>

#define N_NODES 50000
#define N_EDGES 600000
#define D 128
#define BN 128   // nodes per block in k_layer
#define BK 32    // k-chunk
#define BPAD 132 // B_s row stride (floats)
#define SCAN_BLOCKS ((N_NODES + 255) / 256)   // 196

// ---------------- CSR build ----------------

__global__ void k_count(const int* __restrict__ dst, int* __restrict__ cnt) {
    int e = blockIdx.x * blockDim.x + threadIdx.x;
    if (e < N_EDGES) atomicAdd(&cnt[dst[e]], 1);
}

__global__ void k_scan1(const int* __restrict__ cnt, int* __restrict__ off,
                        int* __restrict__ partial) {
    __shared__ int sdata[256];
    const int t = threadIdx.x;
    const int i = blockIdx.x * 256 + t;
    int v = (i < N_NODES) ? cnt[i] : 0;
    sdata[t] = v;
    __syncthreads();
    for (int d = 1; d < 256; d <<= 1) {
        int u = (t >= d) ? sdata[t - d] : 0;
        __syncthreads();
        sdata[t] += u;
        __syncthreads();
    }
    if (i < N_NODES) off[i] = sdata[t] - v;
    if (t == 255) partial[blockIdx.x] = sdata[255];
}

__global__ void k_scan2(int* __restrict__ partial) {
    __shared__ int sdata[256];
    const int t = threadIdx.x;
    int v = (t < SCAN_BLOCKS) ? partial[t] : 0;
    sdata[t] = v;
    __syncthreads();
    for (int d = 1; d < 256; d <<= 1) {
        int u = (t >= d) ? sdata[t - d] : 0;
        __syncthreads();
        sdata[t] += u;
        __syncthreads();
    }
    if (t < SCAN_BLOCKS) partial[t] = sdata[t] - v;
}

__global__ void k_scan3(int* __restrict__ off, const int* __restrict__ partial,
                        int* __restrict__ cursor) {
    const int i = blockIdx.x * 256 + threadIdx.x;
    if (i < N_NODES) {
        int o = off[i] + partial[blockIdx.x];
        off[i] = o;
        cursor[i] = o;
    }
    if (i == 0) off[N_NODES] = N_EDGES;
}

__global__ void k_bucket(const int* __restrict__ src, const int* __restrict__ dst,
                         int* __restrict__ cursor, int* __restrict__ ebuf) {
    int e = blockIdx.x * blockDim.x + threadIdx.x;
    if (e < N_EDGES) {
        int p = atomicAdd(&cursor[dst[e]], 1);
        ebuf[p] = src[e];
    }
}

// ---------------- pull-gather mean ----------------
__global__ void k_gather(const int* __restrict__ off, const int* __restrict__ ebuf,
                         const float* __restrict__ xin, float* __restrict__ mean) {
    int tid = blockIdx.x * blockDim.x + threadIdx.x;
    int node = tid >> 5;
    int q = tid & 31;
    int s0 = off[node], s1 = off[node + 1];
    float4 acc = make_float4(0.f, 0.f, 0.f, 0.f);
    int e = s0;
    for (; e + 4 <= s1; e += 4) {
        int sa = ebuf[e], sb = ebuf[e + 1], sc = ebuf[e + 2], sd = ebuf[e + 3];
        float4 va = ((const float4*)(xin + (size_t)sa * D))[q];
        float4 vb = ((const float4*)(xin + (size_t)sb * D))[q];
        float4 vc = ((const float4*)(xin + (size_t)sc * D))[q];
        float4 vd = ((const float4*)(xin + (size_t)sd * D))[q];
        acc.x += va.x + vb.x + vc.x + vd.x;
        acc.y += va.y + vb.y + vc.y + vd.y;
        acc.z += va.z + vb.z + vc.z + vd.z;
        acc.w += va.w + vb.w + vc.w + vd.w;
    }
    for (; e < s1; ++e) {
        int sa = ebuf[e];
        float4 va = ((const float4*)(xin + (size_t)sa * D))[q];
        acc.x += va.x; acc.y += va.y; acc.z += va.z; acc.w += va.w;
    }
    float inv = (s1 > s0) ? 1.0f / (float)(s1 - s0) : 0.0f;
    acc.x *= inv; acc.y *= inv; acc.z *= inv; acc.w *= inv;
    ((float4*)(mean + (size_t)node * D))[q] = acc;
}

// ---------------- LDS-tiled dual GEMM layer ----------------
// B_s layout: even float4-groups of features at cols 0..63, odd groups at 64..127:
//   col(f) = (f&3) + ((f>>3)<<2) + (((f>>2)&1)<<6), row stride BPAD=132.
// Fragment reads b0 @ B_s[k][4*tcol], b1 @ B_s[k][4*tcol+64]: 16-B stride across
// lanes -> every bank exactly 2 accesses = b128 minimum (conflict-free).
template <bool RELU>
__global__ void __launch_bounds__(256) k_layer(
    const float* __restrict__ mean, const float* __restrict__ xin,
    const float* __restrict__ Wl, const float* __restrict__ bias,
    const float* __restrict__ Wr, float* __restrict__ out) {
    __shared__ float A_s[BN][36];
    __shared__ float B_s[BK][BPAD];

    const int t = threadIdx.x;
    const int node0 = blockIdx.x * BN;
    const int tcol = t & 15;
    const int trow = t >> 4;
    const int f0 = tcol * 8;

    float acc[8][8];
#pragma unroll
    for (int j = 0; j < 8; ++j)
#pragma unroll
        for (int i = 0; i < 8; ++i) acc[j][i] = 0.f;

    for (int chunk = 0; chunk < 8; ++chunk) {
        const float* Asrc = (chunk < 4) ? mean : xin;
        const float* Wsrc = (chunk < 4) ? Wl : Wr;
        const int kc = (chunk & 3) * BK;

#pragma unroll
        for (int l = 0; l < 4; ++l) {
            int idx = l * 256 + t;
            int row = idx >> 3, c4 = (idx & 7) * 4;
            float4 v = make_float4(0.f, 0.f, 0.f, 0.f);
            int node = node0 + row;
            if (node < N_NODES)
                v = *(const float4*)(Asrc + (size_t)node * D + kc + c4);
            *(float4*)(&A_s[row][c4]) = v;
        }
#pragma unroll
        for (int l = 0; l < 4; ++l) {
            int fi = l * 256 + t;
            int f = fi >> 3, q = fi & 7;
            float4 v = *(const float4*)(Wsrc + (size_t)f * D + kc + q * 4);
            int cf = (f & 3) + ((f >> 3) << 2) + (((f >> 2) & 1) << 6);
            B_s[q * 4 + 0][cf] = v.x;
            B_s[q * 4 + 1][cf] = v.y;
            B_s[q * 4 + 2][cf] = v.z;
            B_s[q * 4 + 3][cf] = v.w;
        }
        __syncthreads();

#pragma unroll 2
        for (int k4 = 0; k4 < BK; k4 += 4) {
            float4 a[8];
#pragma unroll
            for (int j = 0; j < 8; ++j)
                a[j] = *(const float4*)(&A_s[trow + 16 * j][k4]);
#pragma unroll
            for (int kk = 0; kk < 4; ++kk) {
                float4 b0 = *(const float4*)(&B_s[k4 + kk][tcol * 4]);
                float4 b1 = *(const float4*)(&B_s[k4 + kk][tcol * 4 + 64]);
                float bb[8] = {b0.x, b0.y, b0.z, b0.w, b1.x, b1.y, b1.z, b1.w};
#pragma unroll
                for (int j = 0; j < 8; ++j) {
                    float av = (kk == 0) ? a[j].x : (kk == 1) ? a[j].y
                             : (kk == 2) ? a[j].z : a[j].w;
#pragma unroll
                    for (int i = 0; i < 8; ++i)
                        acc[j][i] += av * bb[i];
                }
            }
        }
        __syncthreads();
    }

    float4 bv0 = *(const float4*)(bias + f0);
    float4 bv1 = *(const float4*)(bias + f0 + 4);
#pragma unroll
    for (int j = 0; j < 8; ++j) {
        int node = node0 + trow + 16 * j;
        if (node >= N_NODES) continue;
        float o[8];
        o[0] = acc[j][0] + bv0.x; o[1] = acc[j][1] + bv0.y;
        o[2] = acc[j][2] + bv0.z; o[3] = acc[j][3] + bv0.w;
        o[4] = acc[j][4] + bv1.x; o[5] = acc[j][5] + bv1.y;
        o[6] = acc[j][6] + bv1.z; o[7] = acc[j][7] + bv1.w;
        if (RELU) {
#pragma unroll
            for (int i = 0; i < 8; ++i) o[i] = o[i] > 0.f ? o[i] : 0.2f * o[i];
        }
        float* orow = out + (size_t)node * D + f0;
        *(float4*)(orow)     = make_float4(o[0], o[1], o[2], o[3]);
        *(float4*)(orow + 4) = make_float4(o[4], o[5], o[6], o[7]);
    }
}

// ---------------- host launch ----------------

extern "C" void kernel_launch(void* const* d_in, const int* in_sizes, int n_in,
                              void* d_out, int out_size, void* d_ws, size_t ws_size,
                              hipStream_t stream) {
    (void)in_sizes; (void)n_in; (void)out_size; (void)ws_size;

    const float* x   = (const float*)d_in[0];
    const int*   ei  = (const int*)d_in[1];
    const float* W1l = (const float*)d_in[2];
    const float* b1  = (const float*)d_in[3];
    const float* W1r = (const float*)d_in[4];
    const float* W2l = (const float*)d_in[5];
    const float* b2  = (const float*)d_in[6];
    const float* W2r = (const float*)d_in[7];

    const int* src = ei;
    const int* dst = ei + N_EDGES;

    char* ws = (char*)d_ws;
    int*   cnt     = (int*)(ws + 0);          // 200,000 B
    int*   off     = (int*)(ws + 200064);     // 200,004 B
    int*   cursor  = (int*)(ws + 400128);     // 200,000 B
    int*   partial = (int*)(ws + 600192);     // 784 B (pad to 1024)
    int*   ebuf    = (int*)(ws + 601216);     // 2,400,000 B
    float* mean    = (float*)(ws + 3001216);  // 25,600,000 B
    float* h       = (float*)(ws + 28601216); // 25,600,000 B
    float* out     = (float*)d_out;

    hipMemsetAsync(cnt, 0, N_NODES * sizeof(int), stream);
    k_count<<<(N_EDGES + 255) / 256, 256, 0, stream>>>(dst, cnt);
    k_scan1<<<SCAN_BLOCKS, 256, 0, stream>>>(cnt, off, partial);
    k_scan2<<<1, 256, 0, stream>>>(partial);
    k_scan3<<<SCAN_BLOCKS, 256, 0, stream>>>(off, partial, cursor);
    k_bucket<<<(N_EDGES + 255) / 256, 256, 0, stream>>>(src, dst, cursor, ebuf);

    k_gather<<<(N_NODES * 32) / 256, 256, 0, stream>>>(off, ebuf, x, mean);
    k_layer<true><<<(N_NODES + BN - 1) / BN, 256, 0, stream>>>(mean, x, W1l, b1, W1r, h);

    k_gather<<<(N_NODES * 32) / 256, 256, 0, stream>>>(off, ebuf, h, mean);
    k_layer<false><<<(N_NODES + BN - 1) / BN, 256, 0, stream>>>(mean, h, W2l, b2, W2r, out);
}

// Round 6
// 275.422 us; speedup vs baseline: 12.8466x; 1.2516x over previous
//
#include <hip/hip_runtime.h>

#define N_NODES 50000
#define N_EDGES 600000
#define D 128
#define SCAN_BLOCKS ((N_NODES + 255) / 256)   // 196

typedef __attribute__((ext_vector_type(8))) short bf16x8;
typedef __attribute__((ext_vector_type(4))) float floatx4;

__device__ inline unsigned int f2bf(float f) {
    unsigned int u = __float_as_uint(f);
    return (u + 0x7FFFu + ((u >> 16) & 1u)) >> 16;   // RNE
}
__device__ inline float bf_lo(unsigned int u) { return __uint_as_float(u << 16); }
__device__ inline float bf_hi(unsigned int u) { return __uint_as_float(u & 0xFFFF0000u); }

// ---------------- CSR build ----------------

__global__ void k_count(const int* __restrict__ dst, int* __restrict__ cnt) {
    int e = blockIdx.x * blockDim.x + threadIdx.x;
    if (e < N_EDGES) atomicAdd(&cnt[dst[e]], 1);
}

__global__ void k_scan1(const int* __restrict__ cnt, int* __restrict__ off,
                        int* __restrict__ partial) {
    __shared__ int sdata[256];
    const int t = threadIdx.x;
    const int i = blockIdx.x * 256 + t;
    int v = (i < N_NODES) ? cnt[i] : 0;
    sdata[t] = v;
    __syncthreads();
    for (int d = 1; d < 256; d <<= 1) {
        int u = (t >= d) ? sdata[t - d] : 0;
        __syncthreads();
        sdata[t] += u;
        __syncthreads();
    }
    if (i < N_NODES) off[i] = sdata[t] - v;
    if (t == 255) partial[blockIdx.x] = sdata[255];
}

__global__ void k_scan2(int* __restrict__ partial) {
    __shared__ int sdata[256];
    const int t = threadIdx.x;
    int v = (t < SCAN_BLOCKS) ? partial[t] : 0;
    sdata[t] = v;
    __syncthreads();
    for (int d = 1; d < 256; d <<= 1) {
        int u = (t >= d) ? sdata[t - d] : 0;
        __syncthreads();
        sdata[t] += u;
        __syncthreads();
    }
    if (t < SCAN_BLOCKS) partial[t] = sdata[t] - v;
}

__global__ void k_scan3(int* __restrict__ off, const int* __restrict__ partial,
                        int* __restrict__ cursor) {
    const int i = blockIdx.x * 256 + threadIdx.x;
    if (i < N_NODES) {
        int o = off[i] + partial[blockIdx.x];
        off[i] = o;
        cursor[i] = o;
    }
    if (i == 0) off[N_NODES] = N_EDGES;
}

__global__ void k_bucket(const int* __restrict__ src, const int* __restrict__ dst,
                         int* __restrict__ cursor, int* __restrict__ ebuf) {
    int e = blockIdx.x * blockDim.x + threadIdx.x;
    if (e < N_EDGES) {
        int p = atomicAdd(&cursor[dst[e]], 1);
        ebuf[p] = src[e];
    }
}

// ---------------- fp32 -> bf16 conversions ----------------

__global__ void k_cvtx(const float* __restrict__ x, unsigned short* __restrict__ xbf) {
    int i = blockIdx.x * 256 + threadIdx.x;     // one float4 per thread; grid exact
    float4 v = ((const float4*)x)[i];
    uint2 o;
    o.x = f2bf(v.x) | (f2bf(v.y) << 16);
    o.y = f2bf(v.z) | (f2bf(v.w) << 16);
    ((uint2*)xbf)[i] = o;
}

// all four 128x128 weight matrices in one launch (4*16384 = 65536 elems)
__global__ void k_cvtw(const float* __restrict__ a, const float* __restrict__ b,
                       const float* __restrict__ c, const float* __restrict__ d,
                       unsigned short* __restrict__ wbf) {
    int i = blockIdx.x * 256 + threadIdx.x;
    const float* srcs[4] = {a, b, c, d};
    wbf[i] = (unsigned short)f2bf(srcs[i >> 14][i & 16383]);
}

// ---------------- pull-gather mean (bf16 rows, fp32 accum) ----------------
// One thread per (node, 16B chunk = 8 bf16). 16 threads/node, grid exact 3125.
__global__ void k_gather_bf(const int* __restrict__ off, const int* __restrict__ ebuf,
                            const unsigned short* __restrict__ xbf,
                            unsigned short* __restrict__ meanbf) {
    int tid = blockIdx.x * blockDim.x + threadIdx.x;
    int node = tid >> 4;
    int q = tid & 15;
    int s0 = off[node], s1 = off[node + 1];
    float acc[8] = {0.f, 0.f, 0.f, 0.f, 0.f, 0.f, 0.f, 0.f};
    int e = s0;
    for (; e + 4 <= s1; e += 4) {
        int sa = ebuf[e], sb = ebuf[e + 1], sc = ebuf[e + 2], sd = ebuf[e + 3];
        uint4 va = *(const uint4*)(xbf + (size_t)sa * D + q * 8);
        uint4 vb = *(const uint4*)(xbf + (size_t)sb * D + q * 8);
        uint4 vc = *(const uint4*)(xbf + (size_t)sc * D + q * 8);
        uint4 vd = *(const uint4*)(xbf + (size_t)sd * D + q * 8);
        acc[0] += bf_lo(va.x) + bf_lo(vb.x) + bf_lo(vc.x) + bf_lo(vd.x);
        acc[1] += bf_hi(va.x) + bf_hi(vb.x) + bf_hi(vc.x) + bf_hi(vd.x);
        acc[2] += bf_lo(va.y) + bf_lo(vb.y) + bf_lo(vc.y) + bf_lo(vd.y);
        acc[3] += bf_hi(va.y) + bf_hi(vb.y) + bf_hi(vc.y) + bf_hi(vd.y);
        acc[4] += bf_lo(va.z) + bf_lo(vb.z) + bf_lo(vc.z) + bf_lo(vd.z);
        acc[5] += bf_hi(va.z) + bf_hi(vb.z) + bf_hi(vc.z) + bf_hi(vd.z);
        acc[6] += bf_lo(va.w) + bf_lo(vb.w) + bf_lo(vc.w) + bf_lo(vd.w);
        acc[7] += bf_hi(va.w) + bf_hi(vb.w) + bf_hi(vc.w) + bf_hi(vd.w);
    }
    for (; e < s1; ++e) {
        int sa = ebuf[e];
        uint4 va = *(const uint4*)(xbf + (size_t)sa * D + q * 8);
        acc[0] += bf_lo(va.x); acc[1] += bf_hi(va.x);
        acc[2] += bf_lo(va.y); acc[3] += bf_hi(va.y);
        acc[4] += bf_lo(va.z); acc[5] += bf_hi(va.z);
        acc[6] += bf_lo(va.w); acc[7] += bf_hi(va.w);
    }
    float inv = (s1 > s0) ? 1.0f / (float)(s1 - s0) : 0.0f;
    uint4 o;
    o.x = f2bf(acc[0] * inv) | (f2bf(acc[1] * inv) << 16);
    o.y = f2bf(acc[2] * inv) | (f2bf(acc[3] * inv) << 16);
    o.z = f2bf(acc[4] * inv) | (f2bf(acc[5] * inv) << 16);
    o.w = f2bf(acc[6] * inv) | (f2bf(acc[7] * inv) << 16);
    *(uint4*)(meanbf + (size_t)node * D + q * 8) = o;
}

// ---------------- MFMA layer, no LDS ----------------
// Wave w computes nodes [16w,16w+16) x all 128 feats:
//   D[m][n] = sum_k A[m][k] B[k][n],  A = [mean|x] row-major bf16,
//   B[k][n] = W[n][k]  (W row-major bf16 -> direct 16B row reads).
// A-frag: lane = A[m=lane&15][k=quad*8+j]; B-frag: lane = W[n=lane&15][k=quad*8+j]
// C/D: col(n)=lane&15, row(m)=quad*4+reg  [m89-verified layouts]
template <bool RELU, bool OUT_BF16>
__global__ void __launch_bounds__(256) k_layer_mfma(
    const unsigned short* __restrict__ Mbf, const unsigned short* __restrict__ Xbf,
    const unsigned short* __restrict__ Wlbf, const float* __restrict__ bias,
    const unsigned short* __restrict__ Wrbf, void* __restrict__ outp) {
    const int wid = (blockIdx.x * 256 + threadIdx.x) >> 6;
    const int n0 = wid * 16;
    if (n0 >= N_NODES) return;
    const int lane = threadIdx.x & 63;
    const int l15 = lane & 15;
    const int quad = lane >> 4;

    floatx4 acc[8];
#pragma unroll
    for (int i = 0; i < 8; ++i) acc[i] = (floatx4)(0.f);

    const unsigned short* arowM = Mbf + (size_t)(n0 + l15) * D + quad * 8;
    const unsigned short* arowX = Xbf + (size_t)(n0 + l15) * D + quad * 8;

#pragma unroll
    for (int kk = 0; kk < 4; ++kk) {
        bf16x8 a = *(const bf16x8*)(arowM + kk * 32);
#pragma unroll
        for (int nf = 0; nf < 8; ++nf) {
            bf16x8 b = *(const bf16x8*)(Wlbf + (size_t)(nf * 16 + l15) * D + kk * 32 + quad * 8);
            acc[nf] = __builtin_amdgcn_mfma_f32_16x16x32_bf16(a, b, acc[nf], 0, 0, 0);
        }
    }
#pragma unroll
    for (int kk = 0; kk < 4; ++kk) {
        bf16x8 a = *(const bf16x8*)(arowX + kk * 32);
#pragma unroll
        for (int nf = 0; nf < 8; ++nf) {
            bf16x8 b = *(const bf16x8*)(Wrbf + (size_t)(nf * 16 + l15) * D + kk * 32 + quad * 8);
            acc[nf] = __builtin_amdgcn_mfma_f32_16x16x32_bf16(a, b, acc[nf], 0, 0, 0);
        }
    }

#pragma unroll
    for (int nf = 0; nf < 8; ++nf) {
        int f = nf * 16 + l15;
        float bv = bias[f];
#pragma unroll
        for (int r = 0; r < 4; ++r) {
            float v = acc[nf][r] + bv;
            if (RELU) v = v > 0.f ? v : 0.2f * v;
            int node = n0 + quad * 4 + r;
            if (OUT_BF16)
                ((unsigned short*)outp)[(size_t)node * D + f] = (unsigned short)f2bf(v);
            else
                ((float*)outp)[(size_t)node * D + f] = v;
        }
    }
}

// ---------------- host launch ----------------

extern "C" void kernel_launch(void* const* d_in, const int* in_sizes, int n_in,
                              void* d_out, int out_size, void* d_ws, size_t ws_size,
                              hipStream_t stream) {
    (void)in_sizes; (void)n_in; (void)out_size; (void)ws_size;

    const float* x   = (const float*)d_in[0];
    const int*   ei  = (const int*)d_in[1];
    const float* W1l = (const float*)d_in[2];
    const float* b1  = (const float*)d_in[3];
    const float* W1r = (const float*)d_in[4];
    const float* W2l = (const float*)d_in[5];
    const float* b2  = (const float*)d_in[6];
    const float* W2r = (const float*)d_in[7];

    const int* src = ei;
    const int* dst = ei + N_EDGES;

    char* ws = (char*)d_ws;
    int*   cnt     = (int*)(ws + 0);                 // 200,000 B
    int*   off     = (int*)(ws + 200064);            // 200,004 B
    int*   cursor  = (int*)(ws + 400128);            // 200,000 B
    int*   partial = (int*)(ws + 600192);            // 1,024 B
    int*   ebuf    = (int*)(ws + 601216);            // 2,400,000 B
    unsigned short* wbf    = (unsigned short*)(ws + 3001216);   // 131,072 B (W1l,W1r,W2l,W2r)
    unsigned short* xbf    = (unsigned short*)(ws + 3132288);   // 12,800,000 B
    unsigned short* meanbf = (unsigned short*)(ws + 15932288);  // 12,800,000 B
    unsigned short* hbf    = (unsigned short*)(ws + 28732288);  // 12,800,000 B
    float* out = (float*)d_out;

    unsigned short* w1l_bf = wbf;
    unsigned short* w1r_bf = wbf + 16384;
    unsigned short* w2l_bf = wbf + 32768;
    unsigned short* w2r_bf = wbf + 49152;

    hipMemsetAsync(cnt, 0, N_NODES * sizeof(int), stream);
    k_count<<<(N_EDGES + 255) / 256, 256, 0, stream>>>(dst, cnt);
    k_scan1<<<SCAN_BLOCKS, 256, 0, stream>>>(cnt, off, partial);
    k_scan2<<<1, 256, 0, stream>>>(partial);
    k_scan3<<<SCAN_BLOCKS, 256, 0, stream>>>(off, partial, cursor);
    k_bucket<<<(N_EDGES + 255) / 256, 256, 0, stream>>>(src, dst, cursor, ebuf);

    k_cvtx<<<(N_NODES * D / 4) / 256, 256, 0, stream>>>(x, xbf);          // 6250 blocks
    k_cvtw<<<65536 / 256, 256, 0, stream>>>(W1l, W1r, W2l, W2r, wbf);

    k_gather_bf<<<(N_NODES * 16) / 256, 256, 0, stream>>>(off, ebuf, xbf, meanbf);
    k_layer_mfma<true, true><<<(N_NODES / 16 + 3) / 4, 256, 0, stream>>>(
        meanbf, xbf, w1l_bf, b1, w1r_bf, (void*)hbf);

    k_gather_bf<<<(N_NODES * 16) / 256, 256, 0, stream>>>(off, ebuf, hbf, meanbf);
    k_layer_mfma<false, false><<<(N_NODES / 16 + 3) / 4, 256, 0, stream>>>(
        meanbf, hbf, w2l_bf, b2, w2r_bf, (void*)out);
}

// Round 7
// 251.830 us; speedup vs baseline: 14.0501x; 1.0937x over previous
//
#include <hip/hip_runtime.h>

#define N_NODES 50000
#define N_EDGES 600000
#define D 128
#define SCAN_BLOCKS ((N_NODES + 255) / 256)   // 196

typedef __attribute__((ext_vector_type(8))) short bf16x8;
typedef __attribute__((ext_vector_type(4))) float floatx4;

__device__ inline unsigned int f2bf(float f) {
    unsigned int u = __float_as_uint(f);
    return (u + 0x7FFFu + ((u >> 16) & 1u)) >> 16;   // RNE
}
__device__ inline float bf_lo(unsigned int u) { return __uint_as_float(u << 16); }
__device__ inline float bf_hi(unsigned int u) { return __uint_as_float(u & 0xFFFF0000u); }

// ---------------- fused prep: cvt x -> bf16, cvt W -> bf16, degree count ----
// blocks [0,6250): x conversion (1 float4/thread)
// blocks [6250,6506): weight conversion (4 * 128*128 elems)
// blocks [6506,8850): degree count
__global__ void k_prep(const float* __restrict__ x, unsigned short* __restrict__ xbf,
                       const float* __restrict__ wa, const float* __restrict__ wb,
                       const float* __restrict__ wc, const float* __restrict__ wd,
                       unsigned short* __restrict__ wbf,
                       const int* __restrict__ dst, int* __restrict__ cnt) {
    const int b = blockIdx.x;
    const int t = threadIdx.x;
    if (b < 6250) {
        int i = b * 256 + t;
        float4 v = ((const float4*)x)[i];
        uint2 o;
        o.x = f2bf(v.x) | (f2bf(v.y) << 16);
        o.y = f2bf(v.z) | (f2bf(v.w) << 16);
        ((uint2*)xbf)[i] = o;
    } else if (b < 6506) {
        int i = (b - 6250) * 256 + t;
        const float* srcs[4] = {wa, wb, wc, wd};
        wbf[i] = (unsigned short)f2bf(srcs[i >> 14][i & 16383]);
    } else {
        int e = (b - 6506) * 256 + t;
        if (e < N_EDGES) atomicAdd(&cnt[dst[e]], 1);
    }
}

// ---------------- CSR scan + bucket ----------------

__global__ void k_scan1(const int* __restrict__ cnt, int* __restrict__ off,
                        int* __restrict__ partial) {
    __shared__ int sdata[256];
    const int t = threadIdx.x;
    const int i = blockIdx.x * 256 + t;
    int v = (i < N_NODES) ? cnt[i] : 0;
    sdata[t] = v;
    __syncthreads();
    for (int d = 1; d < 256; d <<= 1) {
        int u = (t >= d) ? sdata[t - d] : 0;
        __syncthreads();
        sdata[t] += u;
        __syncthreads();
    }
    if (i < N_NODES) off[i] = sdata[t] - v;
    if (t == 255) partial[blockIdx.x] = sdata[255];
}

__global__ void k_scan2(int* __restrict__ partial) {
    __shared__ int sdata[256];
    const int t = threadIdx.x;
    int v = (t < SCAN_BLOCKS) ? partial[t] : 0;
    sdata[t] = v;
    __syncthreads();
    for (int d = 1; d < 256; d <<= 1) {
        int u = (t >= d) ? sdata[t - d] : 0;
        __syncthreads();
        sdata[t] += u;
        __syncthreads();
    }
    if (t < SCAN_BLOCKS) partial[t] = sdata[t] - v;
}

__global__ void k_scan3(int* __restrict__ off, const int* __restrict__ partial,
                        int* __restrict__ cursor) {
    const int i = blockIdx.x * 256 + threadIdx.x;
    if (i < N_NODES) {
        int o = off[i] + partial[blockIdx.x];
        off[i] = o;
        cursor[i] = o;
    }
    if (i == 0) off[N_NODES] = N_EDGES;
}

__global__ void k_bucket(const int* __restrict__ src, const int* __restrict__ dst,
                         int* __restrict__ cursor, int* __restrict__ ebuf) {
    int e = blockIdx.x * blockDim.x + threadIdx.x;
    if (e < N_EDGES) {
        int p = atomicAdd(&cursor[dst[e]], 1);
        ebuf[p] = src[e];
    }
}

// ---------------- fused gather + MFMA layer ----------------
// Block = 256 threads = 16 nodes.
// Phase 1 (gather): thread (nl=t>>4, q=t&15) accumulates mean of node node0+nl,
//   cols [8q, 8q+8) in fp32; 16 consecutive lanes/node -> coalesced 256 B row
//   reads, no divergence within the 16-lane group. Result -> bf16 LDS tile.
// Phase 2 (MFMA): wave wv computes feats [32*wv, 32*wv+32) for the 16 nodes.
//   A(mean) from LDS, A(x)/B(W rows) from global. Layouts = R6-validated:
//   A: lane=(l15,quad) -> row l15, k = quad*8 + kk*32 ; C/D: col=l15, row=quad*4+r.
template <bool RELU, bool OUT_BF16>
__global__ void __launch_bounds__(256) k_gather_layer(
    const int* __restrict__ off, const int* __restrict__ ebuf,
    const unsigned short* __restrict__ Xbf,
    const unsigned short* __restrict__ Wlbf, const float* __restrict__ bias,
    const unsigned short* __restrict__ Wrbf, void* __restrict__ outp) {
    __shared__ unsigned short tile[16][136];   // 136*2 = 272 B row stride (16B-mult)

    const int t = threadIdx.x;
    const int node0 = blockIdx.x * 16;         // grid 3125 -> exact

    // ---- phase 1: gather mean ----
    {
        const int nl = t >> 4, q = t & 15;
        const int node = node0 + nl;
        int s0 = off[node], s1 = off[node + 1];
        float acc[8] = {0.f, 0.f, 0.f, 0.f, 0.f, 0.f, 0.f, 0.f};
        int e = s0;
        for (; e + 4 <= s1; e += 4) {
            int sa = ebuf[e], sb = ebuf[e + 1], sc = ebuf[e + 2], sd = ebuf[e + 3];
            uint4 va = *(const uint4*)(Xbf + (size_t)sa * D + q * 8);
            uint4 vb = *(const uint4*)(Xbf + (size_t)sb * D + q * 8);
            uint4 vc = *(const uint4*)(Xbf + (size_t)sc * D + q * 8);
            uint4 vd = *(const uint4*)(Xbf + (size_t)sd * D + q * 8);
            acc[0] += bf_lo(va.x) + bf_lo(vb.x) + bf_lo(vc.x) + bf_lo(vd.x);
            acc[1] += bf_hi(va.x) + bf_hi(vb.x) + bf_hi(vc.x) + bf_hi(vd.x);
            acc[2] += bf_lo(va.y) + bf_lo(vb.y) + bf_lo(vc.y) + bf_lo(vd.y);
            acc[3] += bf_hi(va.y) + bf_hi(vb.y) + bf_hi(vc.y) + bf_hi(vd.y);
            acc[4] += bf_lo(va.z) + bf_lo(vb.z) + bf_lo(vc.z) + bf_lo(vd.z);
            acc[5] += bf_hi(va.z) + bf_hi(vb.z) + bf_hi(vc.z) + bf_hi(vd.z);
            acc[6] += bf_lo(va.w) + bf_lo(vb.w) + bf_lo(vc.w) + bf_lo(vd.w);
            acc[7] += bf_hi(va.w) + bf_hi(vb.w) + bf_hi(vc.w) + bf_hi(vd.w);
        }
        for (; e < s1; ++e) {
            int sa = ebuf[e];
            uint4 va = *(const uint4*)(Xbf + (size_t)sa * D + q * 8);
            acc[0] += bf_lo(va.x); acc[1] += bf_hi(va.x);
            acc[2] += bf_lo(va.y); acc[3] += bf_hi(va.y);
            acc[4] += bf_lo(va.z); acc[5] += bf_hi(va.z);
            acc[6] += bf_lo(va.w); acc[7] += bf_hi(va.w);
        }
        float inv = (s1 > s0) ? 1.0f / (float)(s1 - s0) : 0.0f;
        uint4 o;
        o.x = f2bf(acc[0] * inv) | (f2bf(acc[1] * inv) << 16);
        o.y = f2bf(acc[2] * inv) | (f2bf(acc[3] * inv) << 16);
        o.z = f2bf(acc[4] * inv) | (f2bf(acc[5] * inv) << 16);
        o.w = f2bf(acc[6] * inv) | (f2bf(acc[7] * inv) << 16);
        *(uint4*)(&tile[nl][q * 8]) = o;
    }
    __syncthreads();

    // ---- phase 2: MFMA ----
    const int lane = t & 63;
    const int wv = t >> 6;                 // wave id 0..3 -> feats [32wv, 32wv+32)
    const int l15 = lane & 15;
    const int quad = lane >> 4;

    floatx4 c0 = (floatx4)(0.f), c1 = (floatx4)(0.f);
    const int nf0 = wv * 2, nf1 = wv * 2 + 1;

    const unsigned short* mrow = &tile[l15][quad * 8];
    const unsigned short* arowX = Xbf + (size_t)(node0 + l15) * D + quad * 8;

#pragma unroll
    for (int kk = 0; kk < 4; ++kk) {
        bf16x8 a = *(const bf16x8*)(mrow + kk * 32);
        bf16x8 b0 = *(const bf16x8*)(Wlbf + (size_t)(nf0 * 16 + l15) * D + kk * 32 + quad * 8);
        bf16x8 b1 = *(const bf16x8*)(Wlbf + (size_t)(nf1 * 16 + l15) * D + kk * 32 + quad * 8);
        c0 = __builtin_amdgcn_mfma_f32_16x16x32_bf16(a, b0, c0, 0, 0, 0);
        c1 = __builtin_amdgcn_mfma_f32_16x16x32_bf16(a, b1, c1, 0, 0, 0);
    }
#pragma unroll
    for (int kk = 0; kk < 4; ++kk) {
        bf16x8 a = *(const bf16x8*)(arowX + kk * 32);
        bf16x8 b0 = *(const bf16x8*)(Wrbf + (size_t)(nf0 * 16 + l15) * D + kk * 32 + quad * 8);
        bf16x8 b1 = *(const bf16x8*)(Wrbf + (size_t)(nf1 * 16 + l15) * D + kk * 32 + quad * 8);
        c0 = __builtin_amdgcn_mfma_f32_16x16x32_bf16(a, b0, c0, 0, 0, 0);
        c1 = __builtin_amdgcn_mfma_f32_16x16x32_bf16(a, b1, c1, 0, 0, 0);
    }

#pragma unroll
    for (int j = 0; j < 2; ++j) {
        floatx4 c = j ? c1 : c0;
        int f = (wv * 2 + j) * 16 + l15;
        float bv = bias[f];
#pragma unroll
        for (int r = 0; r < 4; ++r) {
            float v = c[r] + bv;
            if (RELU) v = v > 0.f ? v : 0.2f * v;
            int node = node0 + quad * 4 + r;
            if (OUT_BF16)
                ((unsigned short*)outp)[(size_t)node * D + f] = (unsigned short)f2bf(v);
            else
                ((float*)outp)[(size_t)node * D + f] = v;
        }
    }
}

// ---------------- host launch ----------------

extern "C" void kernel_launch(void* const* d_in, const int* in_sizes, int n_in,
                              void* d_out, int out_size, void* d_ws, size_t ws_size,
                              hipStream_t stream) {
    (void)in_sizes; (void)n_in; (void)out_size; (void)ws_size;

    const float* x   = (const float*)d_in[0];
    const int*   ei  = (const int*)d_in[1];
    const float* W1l = (const float*)d_in[2];
    const float* b1  = (const float*)d_in[3];
    const float* W1r = (const float*)d_in[4];
    const float* W2l = (const float*)d_in[5];
    const float* b2  = (const float*)d_in[6];
    const float* W2r = (const float*)d_in[7];

    const int* src = ei;
    const int* dst = ei + N_EDGES;

    char* ws = (char*)d_ws;
    int*   cnt     = (int*)(ws + 0);                 // 200,000 B
    int*   off     = (int*)(ws + 200064);            // 200,004 B
    int*   cursor  = (int*)(ws + 400128);            // 200,000 B
    int*   partial = (int*)(ws + 600192);            // 1,024 B
    int*   ebuf    = (int*)(ws + 601216);            // 2,400,000 B
    unsigned short* wbf = (unsigned short*)(ws + 3001216);   // 131,072 B
    unsigned short* xbf = (unsigned short*)(ws + 3132288);   // 12,800,000 B
    unsigned short* hbf = (unsigned short*)(ws + 15932288);  // 12,800,000 B
    float* out = (float*)d_out;

    unsigned short* w1l_bf = wbf;
    unsigned short* w1r_bf = wbf + 16384;
    unsigned short* w2l_bf = wbf + 32768;
    unsigned short* w2r_bf = wbf + 49152;

    hipMemsetAsync(cnt, 0, N_NODES * sizeof(int), stream);
    k_prep<<<8850, 256, 0, stream>>>(x, xbf, W1l, W1r, W2l, W2r, wbf, dst, cnt);
    k_scan1<<<SCAN_BLOCKS, 256, 0, stream>>>(cnt, off, partial);
    k_scan2<<<1, 256, 0, stream>>>(partial);
    k_scan3<<<SCAN_BLOCKS, 256, 0, stream>>>(off, partial, cursor);
    k_bucket<<<(N_EDGES + 255) / 256, 256, 0, stream>>>(src, dst, cursor, ebuf);

    k_gather_layer<true, true><<<N_NODES / 16, 256, 0, stream>>>(
        off, ebuf, xbf, w1l_bf, b1, w1r_bf, (void*)hbf);
    k_gather_layer<false, false><<<N_NODES / 16, 256, 0, stream>>>(
        off, ebuf, hbf, w2l_bf, b2, w2r_bf, (void*)out);
}